// Round 10
// baseline (14393.176 us; speedup 1.0000x reference)
//
#include <hip/hip_runtime.h>
#include <cstdint>
#include <cmath>

// ============================================================================
// Bidirectional 2-layer GRU, B=64 S=1024 I=H=512, output = last-step concat @ fc.
//   forward : 1024-step recurrence, persistent kernel, 64 blocks (2 layers x
//             32 col-slices), block = 64 rows x 16 cols, gates in-register.
//   backward: only scan index 0 survives => ONE step per layer with h0=0.
//
// Round-10 = round-9 + off-by-one fix. Layer-1 computes BOTH h1.Wh1 (B in
// 192 VGPRs) and h1.Wi2 (B in LDS) off the same A-loads, shipping layer-2's
// gate pre-activations xg2 through a 4-plane ring; layer-2 per step is
// poll + 12 scalar loads + ONE GEMM + gates. FIX: layer-1 runs an epilogue
// iteration T=1025 producing xg2_1024 = h1_1024 . Wi2 (round 9 never made it,
// layer-2's last step timed out and consumed a stale plane -> absmax 1.36).
// All traffic sc0|sc1 coherence-point-direct (zero cache-maintenance ops);
// counted vmcnt pipeline walled by sched_barrier(0); alive-latch timeout.
// ============================================================================

typedef __attribute__((ext_vector_type(8))) short bf16x8;
typedef __attribute__((ext_vector_type(4))) float f32x4;
typedef __attribute__((ext_vector_type(4))) unsigned int u32x4;

#define DEV static __device__ __forceinline__

DEV unsigned short f2bf(float f) {
  union { float f; uint32_t u; } v; v.f = f;
  uint32_t u = v.u;
  return (unsigned short)((u + (((u >> 16) & 1u) + 0x7fffu)) >> 16);
}
DEV float bf2f(unsigned short h) {
  union { uint32_t u; float f; } v; v.u = ((uint32_t)h) << 16;
  return v.f;
}
DEV float fsig(float x)  { return 1.f / (1.f + __expf(-x)); }
DEV float ftanh(float x) { return 2.f / (1.f + __expf(-2.f * x)) - 1.f; }

static constexpr int Ss = 1024, Ii = 512;

// ---- workspace layout (bytes) ----
static constexpr size_t WIMG_PER_LS = 131072;                  // 96KB hi + 32KB n-lo
static constexpr size_t OFF_WIMG = 0;
static constexpr size_t WIMG_BYTES = (size_t)64 * WIMG_PER_LS; // 8 MB
static constexpr size_t OFF_H1  = OFF_WIMG + WIMG_BYTES;       // 4 planes x 128KB (hi | lo at +64KB)
static constexpr size_t OFF_H2  = OFF_H1 + 524288;
static constexpr size_t OFF_FLG = OFF_H2 + 524288;             // int[64*16] (64B-padded flags)
static constexpr size_t OFF_XG  = OFF_FLG + 4096;              // xg2 ring [4][32][64*48] f32
static constexpr size_t OFF_H2F = OFF_XG + 1572864;            // f32 [64][512]
static constexpr size_t OFF_HB1 = OFF_H2F + 131072;
static constexpr size_t OFF_HB2 = OFF_HB1 + 131072;
static constexpr size_t WS_NEED = OFF_HB2 + 131072;

// ============================================================================
// Weight prep (layout unchanged): per (layer,slice) image, 65536 bf16:
//   bytes [0,49152) Wi-hi | [49152,98304) Wh-hi
//   bytes [98304,114688) Wi n-lo | [114688,131072) Wh n-lo
// ============================================================================
__global__ __launch_bounds__(256) void prep_weights(const float* __restrict__ Wi,
                                                    const float* __restrict__ Wh,
                                                    unsigned short* __restrict__ img) {
  uint32_t idx = blockIdx.x * 256 + threadIdx.x;          // < 4,194,304
  uint32_t ls = idx >> 16;                                // layer*32+slice
  uint32_t off = idx & 65535u;
  int l = (int)(ls >> 5), s = (int)(ls & 31);
  int m, g, cc, kg, kr;
  bool lo = off >= 49152u;
  if (!lo) {
    m = (int)(off / 24576u); uint32_t r = off % 24576u;
    kg = (int)(r / 384u); r %= 384u;
    int c = (int)(r >> 3); kr = (int)(r & 7u);
    g = c >> 4; cc = c & 15;
  } else {
    uint32_t o2 = off - 49152u;
    m = (int)(o2 >> 13); uint32_t r = o2 & 8191u;
    kg = (int)(r >> 7); r &= 127u;
    cc = (int)(r >> 3); kr = (int)(r & 7u);
    g = 2;
  }
  int h = s * 16 + cc, k = kg * 8 + kr;
  const float* W = m ? Wh : Wi;                           // [L][D][3][512][512], d=0
  float v = W[((size_t)(l * 6 + g) * 512 + k) * 512 + h];
  unsigned short hv = f2bf(v);
  if (lo) hv = f2bf(v - bf2f(hv));
  img[(size_t)ls * 65536 + off] = hv;
}

// zero h rings; flags at i*16: layer0 (i<32) = 0, layer1 = 1
__global__ __launch_bounds__(256) void init_state(uint32_t* __restrict__ hz,
                                                  int* __restrict__ flg) {
  int tid = blockIdx.x * 256 + threadIdx.x;
  if (tid < 262144) hz[tid] = 0u;                         // h1+h2 = 1MB
  if (tid < 1024) flg[tid] = ((tid & 15) == 0 && tid >= 512) ? 1 : 0;
}

#define MFMA(AA, BB, CC) CC = __builtin_amdgcn_mfma_f32_16x16x32_bf16(AA, BB, CC, 0, 0, 0)
#define SB0 __builtin_amdgcn_sched_barrier(0)
#define VMWAIT0 asm volatile("s_waitcnt vmcnt(0)" ::: "memory")
#define VMWAIT8 asm volatile("s_waitcnt vmcnt(8)" ::: "memory")
// coherence-point-direct (no cache alloc, no cache maintenance) ops
#define LD16CP(dst, addr) \
  asm volatile("global_load_dwordx4 %0, %1, off sc0 sc1" : "=&v"(dst) : "v"((const void*)(addr)))
#define LD4CPF(dst, addr) \
  asm volatile("global_load_dword %0, %1, off sc0 sc1" : "=&v"(dst) : "v"((const void*)(addr)))
#define ST2CP(addr, val) \
  asm volatile("global_store_short %0, %1, off sc0 sc1" :: "v"((void*)(addr)), "v"((uint32_t)(val)) : "memory")
#define ST4CP(addr, val) \
  asm volatile("global_store_dword %0, %1, off sc0 sc1" :: "v"((void*)(addr)), "v"(val) : "memory")

DEV int pollcp(const int* p) {
  int v;
  asm volatile("global_load_dword %0, %1, off sc0 sc1\ns_waitcnt vmcnt(0)"
               : "=v"(v) : "v"((const void*)p) : "memory");
  return v;
}

// wave-0 combined wait: lane<32 polls layer0 flag[lane] >= tgtA, lane>=32
// polls layer1 flag[lane-32] >= tgtB. Alive-latch timeout: first timeout
// ~0.13s, thereafter 64 spins -> bounded free-run, never hangs.
DEV void wait_combined(int* flg, int tgtA, int tgtB, int lane, int& alive) {
  const int* p = flg + lane * 16;
  const int tgt = (lane < 32) ? tgtA : tgtB;
  const int lim = alive ? (1 << 17) : 64;
  int spins = 0;
  for (;;) {
    int v = pollcp(p);
    if (__all(v >= tgt)) break;
    __builtin_amdgcn_s_sleep(1);
    if (++spins > lim) { alive = 0; break; }
  }
}

// issue 8 pipelined 16B loads: 4 (hi,lo) pairs at BOFF + 64*j (+65536 for lo)
#define ISSUE8(R, ABASE, BOFF)                                                 \
  _Pragma("unroll")                                                            \
  for (int j = 0; j < 4; ++j) {                                                \
    LD16CP(R[2*j],   (ABASE) + (BOFF) + 64 * j);                               \
    LD16CP(R[2*j+1], (ABASE) + (BOFF) + 64 * j + 65536);                       \
  }
// consume 4 pairs: Wh from hB regs (layer's own recurrent weights)
#define MFB_REG(R, b, A0, A1, A2)                                              \
  _Pragma("unroll")                                                            \
  for (int j = 0; j < 4; ++j) {                                                \
    const int kk = 4 * (b) + j;                                                \
    const int kg = 16 * (b) + 4 * j + q;                                       \
    bf16x8 ql = *(const bf16x8*)(lds + 114688 + (size_t)kg * 256 + (size_t)l15 * 16); \
    MFMA(R[2*j], hB[kk*3+0], A0); MFMA(R[2*j+1], hB[kk*3+0], A0);              \
    MFMA(R[2*j], hB[kk*3+1], A1); MFMA(R[2*j+1], hB[kk*3+1], A1);              \
    MFMA(R[2*j], hB[kk*3+2], A2); MFMA(R[2*j+1], hB[kk*3+2], A2);              \
    MFMA(R[2*j], ql, A2);                                                      \
  }
// consume 4 pairs DUAL: Wh1 from hB regs -> ah*, Wi2 from LDS@49152 -> bx*
#define MFB_DUAL(R, b)                                                         \
  _Pragma("unroll")                                                            \
  for (int j = 0; j < 4; ++j) {                                                \
    const int kk = 4 * (b) + j;                                                \
    const int kg = 16 * (b) + 4 * j + q;                                       \
    bf16x8 qlh = *(const bf16x8*)(lds + 114688 + (size_t)kg * 256 + (size_t)l15 * 16); \
    MFMA(R[2*j], hB[kk*3+0], ah0); MFMA(R[2*j+1], hB[kk*3+0], ah0);            \
    MFMA(R[2*j], hB[kk*3+1], ah1); MFMA(R[2*j+1], hB[kk*3+1], ah1);            \
    MFMA(R[2*j], hB[kk*3+2], ah2); MFMA(R[2*j+1], hB[kk*3+2], ah2);            \
    MFMA(R[2*j], qlh, ah2);                                                    \
    const unsigned char* wb2 = lds + 49152 + (size_t)kg * 768 + (size_t)l15 * 16; \
    bf16x8 p0 = *(const bf16x8*)(wb2);                                         \
    bf16x8 p1 = *(const bf16x8*)(wb2 + 256);                                   \
    bf16x8 p2 = *(const bf16x8*)(wb2 + 512);                                   \
    bf16x8 qli = *(const bf16x8*)(lds + 131072 + (size_t)kg * 256 + (size_t)l15 * 16); \
    MFMA(R[2*j], p0, bx0); MFMA(R[2*j+1], p0, bx0);                            \
    MFMA(R[2*j], p1, bx1); MFMA(R[2*j+1], p1, bx1);                            \
    MFMA(R[2*j], p2, bx2); MFMA(R[2*j+1], p2, bx2);                            \
    MFMA(R[2*j], qli, bx2);                                                    \
  }
// pipelined A-load GEMM, consumer macro pluggable
#define HGEMM(ABASE, MFB, A0, A1, A2)                                          \
  {                                                                            \
    bf16x8 fa[8], fb[8];                                                       \
    SB0; ISSUE8(fa, ABASE, 0)  SB0; ISSUE8(fb, ABASE, 256) SB0;                \
    VMWAIT8; SB0; MFB(fa, 0, A0, A1, A2) SB0;                                  \
    ISSUE8(fa, ABASE, 512) SB0; VMWAIT8; SB0; MFB(fb, 1, A0, A1, A2) SB0;      \
    ISSUE8(fb, ABASE, 768) SB0; VMWAIT8; SB0; MFB(fa, 2, A0, A1, A2) SB0;      \
    VMWAIT0; SB0; MFB(fb, 3, A0, A1, A2) SB0;                                  \
  }
#define HGEMM_DUAL(ABASE)                                                      \
  {                                                                            \
    bf16x8 fa[8], fb[8];                                                       \
    SB0; ISSUE8(fa, ABASE, 0)  SB0; ISSUE8(fb, ABASE, 256) SB0;                \
    VMWAIT8; SB0; MFB_DUAL(fa, 0) SB0;                                         \
    ISSUE8(fa, ABASE, 512) SB0; VMWAIT8; SB0; MFB_DUAL(fb, 1) SB0;             \
    ISSUE8(fb, ABASE, 768) SB0; VMWAIT8; SB0; MFB_DUAL(fa, 2) SB0;             \
    VMWAIT0; SB0; MFB_DUAL(fb, 3) SB0;                                         \
  }
// x_t . Wi1 : plain cached loads (read-only x), hi/lo built in-reg, B from LDS
#define XGEMM(T0)                                                              \
  {                                                                            \
    const float* xr = xr0 + (size_t)(T0) * Ii;                                 \
    _Pragma("unroll 4")                                                        \
    for (int kk = 0; kk < 16; ++kk) {                                          \
      const int kg = kk * 4 + q;                                               \
      f32x4 va = *(const f32x4*)(xr + kg * 8);                                 \
      f32x4 vb = *(const f32x4*)(xr + kg * 8 + 4);                             \
      bf16x8 ahi, alo;                                                         \
      _Pragma("unroll")                                                        \
      for (int e = 0; e < 4; ++e) {                                            \
        unsigned short ha = f2bf(va[e]);                                       \
        ((unsigned short*)&ahi)[e] = ha;                                       \
        ((unsigned short*)&alo)[e] = f2bf(va[e] - bf2f(ha));                   \
        unsigned short hb_ = f2bf(vb[e]);                                      \
        ((unsigned short*)&ahi)[e + 4] = hb_;                                  \
        ((unsigned short*)&alo)[e + 4] = f2bf(vb[e] - bf2f(hb_));              \
      }                                                                        \
      const unsigned char* wb = lds + (size_t)kg * 768 + (size_t)l15 * 16;     \
      bf16x8 q0 = *(const bf16x8*)(wb);                                        \
      bf16x8 q1 = *(const bf16x8*)(wb + 256);                                  \
      bf16x8 q2 = *(const bf16x8*)(wb + 512);                                  \
      bf16x8 ql = *(const bf16x8*)(lds + 98304 + (size_t)kg * 256 + (size_t)l15 * 16); \
      MFMA(ahi, q0, ax0); MFMA(alo, q0, ax0);                                  \
      MFMA(ahi, q1, ax1); MFMA(alo, q1, ax1);                                  \
      MFMA(ahi, q2, ax2); MFMA(alo, q2, ax2);                                  \
      MFMA(ahi, ql, ax2);                                                      \
    }                                                                          \
  }

// ============================================================================
// Persistent forward recurrence.
// Layer-1 LDS: [0,49152) Wi1-hi | [49152,98304) Wh1-hi -> then Wi2-hi
//              [98304,114688) Wi1-nlo | [114688,131072) Wh1-nlo
//              [131072,147456) Wi2-nlo.        Layer-2: image as-is (128KB).
// ============================================================================
__global__ __launch_bounds__(256, 1) void gru_persistent(const float* __restrict__ x,
                                                         const float* __restrict__ bias,
                                                         unsigned char* __restrict__ ws) {
  __shared__ unsigned char lds[147456];
  const int tid = threadIdx.x, lane = tid & 63, wv = tid >> 6;
  const int bid = blockIdx.x;
  const int xcd = bid & 7;
  const int layer = xcd >> 2;
  const int slice = (xcd & 3) * 8 + (bid >> 3);
  const int l15 = lane & 15, q = lane >> 4;

  { // stage this (layer,slice)'s 128KB image into LDS
    const u32x4* src = (const u32x4*)(ws + OFF_WIMG + (size_t)(layer * 32 + slice) * WIMG_PER_LS);
    u32x4* dst = (u32x4*)lds;
    for (int i = tid; i < 8192; i += 256) dst[i] = src[i];
  }
  __syncthreads();

  // recurrent-side (Wh) hi B-fragments -> 192 VGPRs
  bf16x8 hB[48];
#pragma unroll
  for (int kk = 0; kk < 16; ++kk) {
    const int kg = kk * 4 + q;
    const unsigned char* wb = lds + 49152 + (size_t)kg * 768 + (size_t)l15 * 16;
    hB[kk * 3 + 0] = *(const bf16x8*)(wb);
    hB[kk * 3 + 1] = *(const bf16x8*)(wb + 256);
    hB[kk * 3 + 2] = *(const bf16x8*)(wb + 512);
  }
  __syncthreads();
  if (layer == 0) {  // overwrite Wh1-hi region with Wi2-hi; append Wi2-nlo
    const u32x4* src2 = (const u32x4*)(ws + OFF_WIMG + (size_t)(32 + slice) * WIMG_PER_LS);
    u32x4* dst = (u32x4*)lds;
    for (int i = tid; i < 3072; i += 256) dst[3072 + i] = src2[i];          // ->49152..98304
    for (int i = tid; i < 1024; i += 256) dst[8192 + i] = src2[6144 + i];   // ->131072..147456
  }
  __syncthreads();

  unsigned char* h1b = ws + OFF_H1;
  unsigned char* h2b = ws + OFF_H2;
  int* flg = (int*)(ws + OFF_FLG);
  float* h2f = (float*)(ws + OFF_H2F);

  const int colg = slice * 16 + l15;
  const int row0 = wv * 16 + q * 4;            // first of this lane's 4 C rows
  const int arow = wv * 16 + l15;              // this lane's A row
  const float b0 = bias[(size_t)(layer * 6 + 0) * 512 + colg];
  const float b1 = bias[(size_t)(layer * 6 + 1) * 512 + colg];
  const float b2 = bias[(size_t)(layer * 6 + 2) * 512 + colg];

  int* myflag = flg + (layer * 32 + slice) * 16;
  f32x4 hprev{0.f, 0.f, 0.f, 0.f};
  int alive = 1;

  if (layer == 0) {
    const float* xr0 = x + (size_t)arow * Ss * Ii;
    f32x4 ax0{}, ax1{}, ax2{};
    XGEMM(0)                                   // prologue: x_0 . Wi1
    // T=1..1024: full step. T=1025: EPILOGUE producing xg2_1024 only (fix).
    for (int T = 1; T <= 1025; ++T) {
      // wait: peers' h1_{T-1} ready AND layer-2 past xg/h planes (T-3)
      if (wv == 0) wait_combined(flg, T - 1, T - 3, lane, alive);
      __syncthreads();
      f32x4 ah0{}, ah1{}, ah2{}, bx0{}, bx1{}, bx2{};
      const unsigned char* ab = h1b + (size_t)((T - 1) & 3) * 131072 + (size_t)arow * 1024 + (size_t)q * 16;
      HGEMM_DUAL(ab)                           // ah = h1.Wh1 ; bx = h1.Wi2
      float* xgp = (float*)(ws + OFF_XG + (size_t)((T - 1) & 3) * 393216 + (size_t)slice * 12288);
      if (T <= 1024) {                         // gates + h1_T store (skip at 1025)
        unsigned char* hd = h1b + (size_t)(T & 3) * 131072;
#pragma unroll
        for (int e = 0; e < 4; ++e) {
          float rr = fsig(ax0[e] + ah0[e] + b0);
          float zz = fsig(ax1[e] + ah1[e] + b1);
          float nn = ftanh(ax2[e] + b2 + rr * ah2[e]);
          float hn = (1.f - zz) * nn + zz * hprev[e];
          hprev[e] = hn;
          unsigned short hi = f2bf(hn), lo = f2bf(hn - bf2f(hi));
          size_t ob = (size_t)(row0 + e) * 1024 + (size_t)colg * 2;
          ST2CP(hd + ob, hi); ST2CP(hd + ob + 65536, lo);
        }
      }
#pragma unroll
      for (int e = 0; e < 4; ++e) {            // xg2_{T-1} store (always)
        float* xp = xgp + (size_t)(row0 + e) * 48 + l15;
        ST4CP(xp,      bx0[e]);
        ST4CP(xp + 16, bx1[e]);
        ST4CP(xp + 32, bx2[e]);
      }
      VMWAIT0;                                 // all stores acked at coherence point
      __syncthreads();
      if (tid == 0) ST4CP(myflag, T);
      // next step's x GEMM (plain cached loads, outside counted region)
      if (T < 1024) {
        ax0 = f32x4{}; ax1 = f32x4{}; ax2 = f32x4{};
        XGEMM(T)
      }
    }
  } else {
    // layer 2: at iter T computes h2_{T-1} = gates(xg2_{T-1}, h2_{T-2})
    for (int T = 2; T <= 1025; ++T) {
      if (wv == 0) wait_combined(flg, T, T - 1, lane, alive);   // xg_{T-1}; peers' h2_{T-2}
      __syncthreads();
      f32x4 ah0{}, ah1{}, ah2{};
      const unsigned char* ab2 = h2b + (size_t)((T - 2) & 3) * 131072 + (size_t)arow * 1024 + (size_t)q * 16;
      HGEMM(ab2, MFB_REG, ah0, ah1, ah2)       // h2_{T-2} . Wh2
      // xg2_{T-1}: 12 scalar f32 sc0sc1 loads
      const float* xgp = (const float*)(ws + OFF_XG + (size_t)((T - 1) & 3) * 393216 + (size_t)slice * 12288);
      float xf[12];
      SB0;
#pragma unroll
      for (int e = 0; e < 4; ++e) {
        const float* xp = xgp + (size_t)(row0 + e) * 48 + l15;
        LD4CPF(xf[e * 3 + 0], xp);
        LD4CPF(xf[e * 3 + 1], xp + 16);
        LD4CPF(xf[e * 3 + 2], xp + 32);
      }
      VMWAIT0; SB0;
      unsigned char* hd = h2b + (size_t)((T - 1) & 3) * 131072;
#pragma unroll
      for (int e = 0; e < 4; ++e) {
        float rr = fsig(xf[e * 3 + 0] + ah0[e] + b0);
        float zz = fsig(xf[e * 3 + 1] + ah1[e] + b1);
        float nn = ftanh(xf[e * 3 + 2] + b2 + rr * ah2[e]);
        float hn = (1.f - zz) * nn + zz * hprev[e];
        hprev[e] = hn;
        unsigned short hi = f2bf(hn), lo = f2bf(hn - bf2f(hi));
        size_t ob = (size_t)(row0 + e) * 1024 + (size_t)colg * 2;
        ST2CP(hd + ob, hi); ST2CP(hd + ob + 65536, lo);
        if (T == 1025) h2f[(size_t)(row0 + e) * 512 + colg] = hn;
      }
      VMWAIT0;
      __syncthreads();
      if (tid == 0) ST4CP(myflag, T);
    }
  }
}

// ============================================================================
// Backward direction, first scan step only (h0=0): out = (1-sig(xg1))*tanh(xg2).
// ============================================================================
__global__ __launch_bounds__(256) void gru_bstep(const float* __restrict__ inp, long rstride,
                                                 const float* __restrict__ Wi,
                                                 const float* __restrict__ bias,
                                                 float* __restrict__ out) {
  __shared__ float a[8192];                  // [16][512]
  int tid = threadIdx.x;
  int bg = blockIdx.x >> 4, cg = blockIdx.x & 15;
  for (int j = 0; j < 32; ++j) {
    int idx = j * 256 + tid;
    int r = idx >> 9, k = idx & 511;
    a[idx] = inp[(size_t)(bg * 16 + r) * rstride + k];
  }
  __syncthreads();
  int col = cg * 32 + (tid & 31);
  int r0 = tid >> 5;
  float z0 = bias[512 + col], z1 = z0;
  float n0 = bias[1024 + col], n1 = n0;
  const float* W1 = Wi + (size_t)512 * 512;
  const float* W2 = Wi + (size_t)2 * 512 * 512;
  for (int k = 0; k < 512; ++k) {
    float wz = W1[(size_t)k * 512 + col];
    float wn = W2[(size_t)k * 512 + col];
    float a0 = a[r0 * 512 + k], a1 = a[(r0 + 8) * 512 + k];
    z0 += a0 * wz; z1 += a1 * wz;
    n0 += a0 * wn; n1 += a1 * wn;
  }
  float s0 = fsig(z0), s1 = fsig(z1);
  out[(size_t)(bg * 16 + r0) * 512 + col]     = (1.f - s0) * ftanh(n0);
  out[(size_t)(bg * 16 + r0 + 8) * 512 + col] = (1.f - s1) * ftanh(n1);
}

__global__ __launch_bounds__(256) void fc_kernel(const float* __restrict__ h2f,
                                                 const float* __restrict__ hb2,
                                                 const float* __restrict__ fcw,
                                                 const float* __restrict__ fcb,
                                                 float* __restrict__ out) {
  __shared__ float a[16384];                 // [16][1024]
  int tid = threadIdx.x;
  int bg = blockIdx.x >> 4, cg = blockIdx.x & 15;
  for (int j = 0; j < 32; ++j) {
    int idx = j * 256 + tid;
    int r = idx >> 9, k = idx & 511;
    a[r * 1024 + k]       = h2f[(size_t)(bg * 16 + r) * 512 + k];
    a[r * 1024 + 512 + k] = hb2[(size_t)(bg * 16 + r) * 512 + k];
  }
  __syncthreads();
  int col = cg * 32 + (tid & 31);
  int r0 = tid >> 5;
  float s0 = fcb[col], s1 = fcb[col];
  for (int k = 0; k < 1024; ++k) {
    float wvv = fcw[(size_t)k * 512 + col];
    s0 += a[r0 * 1024 + k] * wvv;
    s1 += a[(r0 + 8) * 1024 + k] * wvv;
  }
  out[(size_t)(bg * 16 + r0) * 512 + col]     = s0;
  out[(size_t)(bg * 16 + r0 + 8) * 512 + col] = s1;
}

extern "C" void kernel_launch(void* const* d_in, const int* in_sizes, int n_in,
                              void* d_out, int out_size, void* d_ws, size_t ws_size,
                              hipStream_t stream) {
  const float* x   = (const float*)d_in[0];
  const float* Wi  = (const float*)d_in[1];
  const float* Wh  = (const float*)d_in[2];
  const float* b   = (const float*)d_in[3];
  const float* fcw = (const float*)d_in[4];
  const float* fcb = (const float*)d_in[5];
  float* out = (float*)d_out;
  unsigned char* ws = (unsigned char*)d_ws;
  if (ws_size < WS_NEED) return;   // visible failure (poisoned out), not corruption

  prep_weights<<<16384, 256, 0, stream>>>(Wi, Wh, (unsigned short*)(ws + OFF_WIMG));
  init_state<<<1024, 256, 0, stream>>>((uint32_t*)(ws + OFF_H1), (int*)(ws + OFF_FLG));
  gru_persistent<<<64, 256, 0, stream>>>(x, b, ws);
  gru_bstep<<<64, 256, 0, stream>>>(x + (size_t)1023 * 512, (long)Ss * Ii,
                                    Wi + (size_t)3 * 512 * 512, b + 3 * 512,
                                    (float*)(ws + OFF_HB1));
  gru_bstep<<<64, 256, 0, stream>>>((const float*)(ws + OFF_HB1), 512L,
                                    Wi + (size_t)9 * 512 * 512, b + 9 * 512,
                                    (float*)(ws + OFF_HB2));
  fc_kernel<<<64, 256, 0, stream>>>((const float*)(ws + OFF_H2F), (const float*)(ws + OFF_HB2),
                                    fcw, fcb, out);
}